// Round 1
// baseline (198.192 us; speedup 1.0000x reference)
//
#include <hip/hip_runtime.h>
#include <hip/hip_fp16.h>

#define T1 512
#define NB 32      // batches
#define NP 96      // 3 pairs * 32 batches
#define DHEAD 64

// ---------------- kernel 1: row-normalize x and y ----------------
__global__ __launch_bounds__(256) void k_normalize(const float* __restrict__ x,
                                                   const float* __restrict__ y,
                                                   float* __restrict__ xn,
                                                   float* __restrict__ yn) {
  int wid  = threadIdx.x >> 6;
  int lane = threadIdx.x & 63;
  int row  = blockIdx.x * 4 + wid;          // 0 .. 32767
  const float* src; float* dst;
  if (row < NB * T1) { src = x + (size_t)row * DHEAD;            dst = xn + (size_t)row * DHEAD; }
  else { int r2 = row - NB * T1; src = y + (size_t)r2 * DHEAD;   dst = yn + (size_t)r2 * DHEAD; }
  float v = src[lane];
  float s = v * v;
  #pragma unroll
  for (int off = 32; off > 0; off >>= 1) s += __shfl_xor(s, off);
  float rn = 1.0f / fmaxf(sqrtf(s), 1e-12f);
  dst[lane] = v * rn;
}

// ---------------- kernel 2: W[p][b][j][i] = exp(-(1 - xn_i . yn_j)) in f16 ----------------
__global__ __launch_bounds__(256) void k_gemm_w(const float* __restrict__ xn,
                                                const float* __restrict__ yn,
                                                __half* __restrict__ W) {
  int pb = blockIdx.z;            // 0..95
  int p  = pb >> 5;               // 0:xy 1:xx 2:yy
  int b  = pb & 31;
  const float* A  = ((p == 2) ? yn : xn) + (size_t)b * T1 * DHEAD;  // i-side
  const float* Bm = ((p == 1) ? xn : yn) + (size_t)b * T1 * DHEAD;  // j-side

  int i0 = blockIdx.x * 64, j0 = blockIdx.y * 64;
  __shared__ float As[64][65];
  __shared__ float Bs[64][65];
  int tid = threadIdx.x;
  #pragma unroll
  for (int q = 0; q < 4; ++q) {
    int idx = tid + q * 256;         // float4 index 0..1023
    int row = idx >> 4;
    int c4  = (idx & 15) << 2;
    float4 av = *reinterpret_cast<const float4*>(A  + (size_t)(i0 + row) * DHEAD + c4);
    As[row][c4+0] = av.x; As[row][c4+1] = av.y; As[row][c4+2] = av.z; As[row][c4+3] = av.w;
    float4 bv = *reinterpret_cast<const float4*>(Bm + (size_t)(j0 + row) * DHEAD + c4);
    Bs[row][c4+0] = bv.x; Bs[row][c4+1] = bv.y; Bs[row][c4+2] = bv.z; Bs[row][c4+3] = bv.w;
  }
  __syncthreads();

  int tx = tid & 15, ty = tid >> 4;   // tx -> i, ty -> j
  float acc[4][4];
  #pragma unroll
  for (int a = 0; a < 4; ++a)
    #pragma unroll
    for (int c = 0; c < 4; ++c) acc[a][c] = 0.f;

  #pragma unroll 4
  for (int k = 0; k < 64; ++k) {
    float av[4], bv[4];
    #pragma unroll
    for (int ic = 0; ic < 4; ++ic) av[ic] = As[tx + (ic << 4)][k];
    #pragma unroll
    for (int jr = 0; jr < 4; ++jr) bv[jr] = Bs[ty + (jr << 4)][k];
    #pragma unroll
    for (int jr = 0; jr < 4; ++jr)
      #pragma unroll
      for (int ic = 0; ic < 4; ++ic)
        acc[jr][ic] = fmaf(av[ic], bv[jr], acc[jr][ic]);
  }

  const float NLOG2E = -1.44269504088896340736f;
  __half* Wp = W + (size_t)pb * (T1 * T1);
  #pragma unroll
  for (int jr = 0; jr < 4; ++jr) {
    int j = j0 + ty + (jr << 4);
    #pragma unroll
    for (int ic = 0; ic < 4; ++ic) {
      int i = i0 + tx + (ic << 4);
      float d = 1.0f - acc[jr][ic];
      float w = exp2f(NLOG2E * d);       // exp(-d)
      Wp[(size_t)j * T1 + i] = __float2half(w);
    }
  }
}

// ---------------- kernel 3: soft-DTW in exp domain, one wave per problem ----------------
// Lane l owns DP rows 8l+1 .. 8l+8. Skewed wavefront: at step t lane l works column
// j = t - l (0-based into W). State V[r] = 2^(B2 - R*log2e) for its 8 rows at the
// previous column; per-cell update is a single FMA; per-column renorm by a power of 2.
__global__ __launch_bounds__(64) void k_dtw(const __half* __restrict__ W,
                                            float* __restrict__ res) {
  int prob = blockIdx.x;
  const __half* Wp = W + (size_t)prob * (T1 * T1);
  int lane = threadIdx.x;

  float V[8];
  #pragma unroll
  for (int r = 0; r < 8; ++r) V[r] = 0.f;
  float nbSaved = (lane == 0) ? 1.0f : 0.0f;   // diag term for r=0 (R[0][0]=0 -> 1)
  float B2 = 0.0f;                              // base, log2 units (integer-valued)

  auto loadW = [&](int t) -> uint4 {
    int j = t - lane;
    if ((unsigned)j < (unsigned)T1) {
      return *reinterpret_cast<const uint4*>(Wp + (size_t)j * T1 + (lane << 3));
    }
    uint4 z; z.x = z.y = z.z = z.w = 0; return z;
  };

  auto step = [&](int t, uint4 raw) {
    // neighbor exchange: lane l-1's bottom-row value + base (previous step state)
    float nbV = __shfl_up(V[7], 1);
    float nbB = __shfl_up(B2, 1);
    if (lane == 0) nbV = 0.f;   // DP row 0 is BIG (=> 0) for j>=1
    int j = t - lane;
    bool active = ((unsigned)j < (unsigned)T1);
    if (active) {
      union { uint4 u; __half h[8]; } cv; cv.u = raw;
      float wv[8];
      #pragma unroll
      for (int r = 0; r < 8; ++r) wv[r] = __half2float(cv.h[r]);

      // convert neighbor value into my base (exact: integer exponent shift)
      float upc = ldexpf(nbV, (int)(B2 - nbB));

      // chained scan down the 8 rows: Vn[r] = w*(diag + left) + w*Vn[r-1]
      float c = fmaf(wv[0], upc, wv[0] * (nbSaved + V[0]));
      float Vn[8]; Vn[0] = c;
      #pragma unroll
      for (int r = 1; r < 8; ++r) {
        c = fmaf(wv[r], c, wv[r] * (V[r-1] + V[r]));
        Vn[r] = c;
      }

      // power-of-2 renormalization (exact)
      float m = fmaxf(fmaxf(fmaxf(Vn[0], Vn[1]), fmaxf(Vn[2], Vn[3])),
                      fmaxf(fmaxf(Vn[4], Vn[5]), fmaxf(Vn[6], Vn[7])));
      int e = (int)((__float_as_uint(m) >> 23) & 0xFF) - 127;
      e = e < -126 ? -126 : (e > 126 ? 126 : e);
      float sc = __uint_as_float((unsigned)(127 - e) << 23);  // 2^(-e)
      #pragma unroll
      for (int r = 0; r < 8; ++r) V[r] = Vn[r] * sc;
      nbSaved = upc * sc;     // this column's up becomes next column's diag
      B2 -= (float)e;
    }
  };

  // prefetch 4 columns ahead to cover L2/L3 latency
  uint4 r0 = loadW(0), r1 = loadW(1), r2 = loadW(2), r3 = loadW(3);
  for (int tb = 0; tb < 576; tb += 4) {
    step(tb + 0, r0); r0 = loadW(tb + 4);
    step(tb + 1, r1); r1 = loadW(tb + 5);
    step(tb + 2, r2); r2 = loadW(tb + 6);
    step(tb + 3, r3); r3 = loadW(tb + 7);
  }

  if (lane == 63) {
    // R[512][512] = (B2 - log2(V[7])) * ln2
    res[prob] = (B2 - log2f(V[7])) * 0.69314718055994530942f;
  }
}

// ---------------- kernel 4: combine ----------------
__global__ void k_combine(const float* __restrict__ res, float* __restrict__ out) {
  int b = threadIdx.x;
  if (b < NB) out[b] = res[b] - 0.5f * (res[NB + b] + res[2 * NB + b]);
}

extern "C" void kernel_launch(void* const* d_in, const int* in_sizes, int n_in,
                              void* d_out, int out_size, void* d_ws, size_t ws_size,
                              hipStream_t stream) {
  const float* x = (const float*)d_in[0];
  const float* y = (const float*)d_in[1];
  float* out = (float*)d_out;

  const size_t xn_off  = 0;
  const size_t yn_off  = (size_t)NB * T1 * DHEAD * sizeof(float);          // 4 MB
  const size_t W_off   = 2 * yn_off;                                        // 8 MB
  const size_t res_off = W_off + (size_t)3 * NB * T1 * T1 * sizeof(__half); // +50.33 MB
  const size_t need    = res_off + NP * sizeof(float);

  if (ws_size < need) {
    // recognizable failure: NaN output (ws too small for W buffer)
    hipMemsetAsync(d_out, 0xFF, (size_t)out_size * sizeof(float), stream);
    return;
  }

  float*  xn  = (float*)((char*)d_ws + xn_off);
  float*  yn  = (float*)((char*)d_ws + yn_off);
  __half* W   = (__half*)((char*)d_ws + W_off);
  float*  res = (float*)((char*)d_ws + res_off);

  hipLaunchKernelGGL(k_normalize, dim3(8192), dim3(256), 0, stream, x, y, xn, yn);
  hipLaunchKernelGGL(k_gemm_w, dim3(8, 8, 96), dim3(256), 0, stream, xn, yn, W);
  hipLaunchKernelGGL(k_dtw, dim3(NP), dim3(64), 0, stream, W, res);
  hipLaunchKernelGGL(k_combine, dim3(1), dim3(64), 0, stream, res, out);
}

// Round 2
// 141.019 us; speedup vs baseline: 1.4054x; 1.4054x over previous
//
#include <hip/hip_runtime.h>
#include <hip/hip_fp16.h>

#define T1 512
#define NB 32      // batches
#define NP 96      // 3 pairs * 32 batches
#define DHEAD 64

// ---------------- kernel 1: row-normalize x and y ----------------
__global__ __launch_bounds__(256) void k_normalize(const float* __restrict__ x,
                                                   const float* __restrict__ y,
                                                   float* __restrict__ xn,
                                                   float* __restrict__ yn) {
  int wid  = threadIdx.x >> 6;
  int lane = threadIdx.x & 63;
  int row  = blockIdx.x * 4 + wid;          // 0 .. 32767
  const float* src; float* dst;
  if (row < NB * T1) { src = x + (size_t)row * DHEAD;            dst = xn + (size_t)row * DHEAD; }
  else { int r2 = row - NB * T1; src = y + (size_t)r2 * DHEAD;   dst = yn + (size_t)r2 * DHEAD; }
  float v = src[lane];
  float s = v * v;
  #pragma unroll
  for (int off = 32; off > 0; off >>= 1) s += __shfl_xor(s, off);
  float rn = 1.0f / fmaxf(sqrtf(s), 1e-12f);
  dst[lane] = v * rn;
}

// ---------------- kernel 2: W[p][b][j][i] = exp(-(1 - xn_i . yn_j)) in f16 ----------------
__global__ __launch_bounds__(256) void k_gemm_w(const float* __restrict__ xn,
                                                const float* __restrict__ yn,
                                                __half* __restrict__ W) {
  int pb = blockIdx.z;            // 0..95
  int p  = pb >> 5;               // 0:xy 1:xx 2:yy
  int b  = pb & 31;
  const float* A  = ((p == 2) ? yn : xn) + (size_t)b * T1 * DHEAD;  // i-side
  const float* Bm = ((p == 1) ? xn : yn) + (size_t)b * T1 * DHEAD;  // j-side

  int i0 = blockIdx.x * 64, j0 = blockIdx.y * 64;
  __shared__ float As[64][65];
  __shared__ float Bs[64][65];
  int tid = threadIdx.x;
  #pragma unroll
  for (int q = 0; q < 4; ++q) {
    int idx = tid + q * 256;         // float4 index 0..1023
    int row = idx >> 4;
    int c4  = (idx & 15) << 2;
    float4 av = *reinterpret_cast<const float4*>(A  + (size_t)(i0 + row) * DHEAD + c4);
    As[row][c4+0] = av.x; As[row][c4+1] = av.y; As[row][c4+2] = av.z; As[row][c4+3] = av.w;
    float4 bv = *reinterpret_cast<const float4*>(Bm + (size_t)(j0 + row) * DHEAD + c4);
    Bs[row][c4+0] = bv.x; Bs[row][c4+1] = bv.y; Bs[row][c4+2] = bv.z; Bs[row][c4+3] = bv.w;
  }
  __syncthreads();

  int tx = tid & 15, ty = tid >> 4;   // tx -> i, ty -> j
  float acc[4][4];
  #pragma unroll
  for (int a = 0; a < 4; ++a)
    #pragma unroll
    for (int c = 0; c < 4; ++c) acc[a][c] = 0.f;

  #pragma unroll 4
  for (int k = 0; k < 64; ++k) {
    float av[4], bv[4];
    #pragma unroll
    for (int ic = 0; ic < 4; ++ic) av[ic] = As[tx + (ic << 4)][k];
    #pragma unroll
    for (int jr = 0; jr < 4; ++jr) bv[jr] = Bs[ty + (jr << 4)][k];
    #pragma unroll
    for (int jr = 0; jr < 4; ++jr)
      #pragma unroll
      for (int ic = 0; ic < 4; ++ic)
        acc[jr][ic] = fmaf(av[ic], bv[jr], acc[jr][ic]);
  }

  const float NLOG2E = -1.44269504088896340736f;
  __half* Wp = W + (size_t)pb * (T1 * T1);
  #pragma unroll
  for (int jr = 0; jr < 4; ++jr) {
    int j = j0 + ty + (jr << 4);
    #pragma unroll
    for (int ic = 0; ic < 4; ++ic) {
      int i = i0 + tx + (ic << 4);
      float d = 1.0f - acc[jr][ic];
      float w = exp2f(NLOG2E * d);       // exp(-d)
      Wp[(size_t)j * T1 + i] = __float2half(w);
    }
  }
}

// ---------------- kernel 3: soft-DTW in exp domain, one wave per problem ----------------
// Lane l owns DP rows 8l+1 .. 8l+8. Skewed wavefront: at step t lane l works W column
// j = t - l. State V[r] = 2^(B2 - R*log2e). Per-cell update = one FMA on the chain.
// Renorm (exact power-of-2) every 8 steps; neighbor base diff dB refreshed only then.
// Prefetch depth 16 (circular reg buffer, fully unrolled -> static indexing) to cover
// ~900cyc HBM latency with ~60cyc steps.
__global__ __launch_bounds__(64) void k_dtw(const __half* __restrict__ W,
                                            float* __restrict__ res) {
  int prob = blockIdx.x;
  const __half* Wp = W + (size_t)prob * (T1 * T1);
  int lane = threadIdx.x;

  float V[8];
  #pragma unroll
  for (int r = 0; r < 8; ++r) V[r] = 0.f;
  float nbSaved = (lane == 0) ? 1.0f : 0.0f;   // diag term for r=0 (R[0][0]=0 -> 1)
  float B2 = 0.0f;      // per-lane base, log2 units (integer-valued, exact in f32)
  float dB = 0.0f;      // B2 - neighbor's B2, refreshed at renorm steps only

  const __half* lp = Wp + (lane << 3);

  auto loadW = [&](int t) -> uint4 {
    int j = t - lane;
    j = j < 0 ? 0 : (j > T1 - 1 ? T1 - 1 : j);   // clamp: no divergent branch on load
    return *reinterpret_cast<const uint4*>(lp + (size_t)j * T1);
  };

  auto step = [&](int t, uint4 raw, bool renorm) {
    float nbV = __shfl_up(V[7], 1);              // neighbor's bottom row, prev column
    if (lane == 0) nbV = 0.f;                    // DP row 0 is BIG (=> 0) for j>=1
    float upc = ldexpf(nbV, (int)dB);            // convert into my base (exact)
    int j = t - lane;
    bool active = ((unsigned)j < (unsigned)T1);
    union { uint4 u; __half h[8]; } cv; cv.u = raw;
    float wv[8];
    #pragma unroll
    for (int r = 0; r < 8; ++r) wv[r] = __half2float(cv.h[r]);
    if (active) {
      // chained scan down the 8 rows: Vn[r] = w*(diag + left) + w*Vn[r-1]
      float c = fmaf(wv[0], upc, wv[0] * (nbSaved + V[0]));
      float Vn[8]; Vn[0] = c;
      #pragma unroll
      for (int r = 1; r < 8; ++r) {
        c = fmaf(wv[r], c, wv[r] * (V[r-1] + V[r]));
        Vn[r] = c;
      }
      if (renorm) {
        float m = fmaxf(fmaxf(fmaxf(Vn[0], Vn[1]), fmaxf(Vn[2], Vn[3])),
                        fmaxf(fmaxf(Vn[4], Vn[5]), fmaxf(Vn[6], Vn[7])));
        int e = (int)((__float_as_uint(m) >> 23) & 0xFF) - 127;
        e = e < -126 ? -126 : (e > 126 ? 126 : e);
        float sc = __uint_as_float((unsigned)(127 - e) << 23);  // 2^(-e), exact
        #pragma unroll
        for (int r = 0; r < 8; ++r) V[r] = Vn[r] * sc;
        nbSaved = upc * sc;
        B2 -= (float)e;
      } else {
        #pragma unroll
        for (int r = 0; r < 8; ++r) V[r] = Vn[r];
        nbSaved = upc;
      }
    }
    if (renorm) {                                // wave-wide: refresh base diff
      float nbB = __shfl_up(B2, 1);
      dB = B2 - nbB;
    }
  };

  uint4 buf[16];
  #pragma unroll
  for (int k = 0; k < 16; ++k) buf[k] = loadW(k);

  for (int tb = 0; tb < 576; tb += 16) {         // 576 = 36 * 16
    #pragma unroll
    for (int k = 0; k < 16; ++k) {
      step(tb + k, buf[k], ((tb + k) & 7) == 7);
      buf[k] = loadW(tb + 16 + k);               // prefetch 16 steps ahead
    }
  }

  if (lane == 63) {
    // R[512][512] = (B2 - log2(V[7])) * ln2
    res[prob] = (B2 - log2f(V[7])) * 0.69314718055994530942f;
  }
}

// ---------------- kernel 4: combine ----------------
__global__ void k_combine(const float* __restrict__ res, float* __restrict__ out) {
  int b = threadIdx.x;
  if (b < NB) out[b] = res[b] - 0.5f * (res[NB + b] + res[2 * NB + b]);
}

extern "C" void kernel_launch(void* const* d_in, const int* in_sizes, int n_in,
                              void* d_out, int out_size, void* d_ws, size_t ws_size,
                              hipStream_t stream) {
  const float* x = (const float*)d_in[0];
  const float* y = (const float*)d_in[1];
  float* out = (float*)d_out;

  const size_t xn_off  = 0;
  const size_t yn_off  = (size_t)NB * T1 * DHEAD * sizeof(float);          // 4 MB
  const size_t W_off   = 2 * yn_off;                                        // 8 MB
  const size_t res_off = W_off + (size_t)3 * NB * T1 * T1 * sizeof(__half); // +50.33 MB
  const size_t need    = res_off + NP * sizeof(float);

  if (ws_size < need) {
    hipMemsetAsync(d_out, 0xFF, (size_t)out_size * sizeof(float), stream);
    return;
  }

  float*  xn  = (float*)((char*)d_ws + xn_off);
  float*  yn  = (float*)((char*)d_ws + yn_off);
  __half* W   = (__half*)((char*)d_ws + W_off);
  float*  res = (float*)((char*)d_ws + res_off);

  hipLaunchKernelGGL(k_normalize, dim3(8192), dim3(256), 0, stream, x, y, xn, yn);
  hipLaunchKernelGGL(k_gemm_w, dim3(8, 8, 96), dim3(256), 0, stream, xn, yn, W);
  hipLaunchKernelGGL(k_dtw, dim3(NP), dim3(64), 0, stream, W, res);
  hipLaunchKernelGGL(k_combine, dim3(1), dim3(64), 0, stream, res, out);
}

// Round 4
// 128.005 us; speedup vs baseline: 1.5483x; 1.1017x over previous
//
#include <hip/hip_runtime.h>
#include <hip/hip_fp16.h>

#define T1 512
#define NB 32      // batches
#define NP 96      // 3 pairs * 32 batches
#define DHEAD 64

typedef __attribute__((ext_vector_type(8))) short bf16x8;
typedef __attribute__((ext_vector_type(4))) float f32x4;

// ---------------- kernel 1: row-normalize x,y -> bf16 ----------------
__global__ __launch_bounds__(256) void k_normalize(const float* __restrict__ x,
                                                   const float* __restrict__ y,
                                                   ushort* __restrict__ xb,
                                                   ushort* __restrict__ yb) {
  int wid  = threadIdx.x >> 6;
  int lane = threadIdx.x & 63;
  int row  = blockIdx.x * 4 + wid;          // 0 .. 32767
  const float* src; ushort* dst;
  if (row < NB * T1) { src = x + (size_t)row * DHEAD;            dst = xb + (size_t)row * DHEAD; }
  else { int r2 = row - NB * T1; src = y + (size_t)r2 * DHEAD;   dst = yb + (size_t)r2 * DHEAD; }
  float v = src[lane];
  float s = v * v;
  #pragma unroll
  for (int off = 32; off > 0; off >>= 1) s += __shfl_xor(s, off);
  float rn = 1.0f / fmaxf(sqrtf(s), 1e-12f);
  float o = v * rn;
  unsigned u = __float_as_uint(o);
  unsigned r = (u + 0x7fffu + ((u >> 16) & 1u)) >> 16;   // RNE to bf16
  dst[lane] = (ushort)r;
}

// ---------------- kernel 2: MFMA bf16 GEMM -> W[p][b][j][i] = exp(-(1-dot)) f16 ----------------
// 256 thr = 4 waves (2x2), tile 128x128, wave tile 64x64. K=64 = 2 mfma k-steps.
// Fragments loaded directly from global (xb/yb K-contiguous, L2-resident).
__global__ __launch_bounds__(256) void k_gemm_w(const ushort* __restrict__ xb,
                                                const ushort* __restrict__ yb,
                                                __half* __restrict__ W) {
  int pb = blockIdx.z;            // 0..95
  int p  = pb >> 5;               // 0:xy 1:xx 2:yy
  int b  = pb & 31;
  const ushort* A  = ((p == 2) ? yb : xb) + (size_t)b * T1 * DHEAD;  // i-side (M)
  const ushort* Bm = ((p == 1) ? xb : yb) + (size_t)b * T1 * DHEAD;  // j-side (N)

  int wid = threadIdx.x >> 6, lane = threadIdx.x & 63;
  int wm = wid >> 1, wn = wid & 1;
  int i0 = blockIdx.x * 128 + wm * 64;
  int j0 = blockIdx.y * 128 + wn * 64;
  int lr = lane & 15, kg = lane >> 4;

  f32x4 acc[4][4];
  #pragma unroll
  for (int ic = 0; ic < 4; ++ic)
    #pragma unroll
    for (int jc = 0; jc < 4; ++jc) acc[ic][jc] = (f32x4){0.f, 0.f, 0.f, 0.f};

  #pragma unroll
  for (int kk = 0; kk < 2; ++kk) {
    int ko = kk * 32 + kg * 8;
    bf16x8 af[4], bf[4];
    #pragma unroll
    for (int ic = 0; ic < 4; ++ic)
      af[ic] = *reinterpret_cast<const bf16x8*>(A + (size_t)(i0 + ic * 16 + lr) * DHEAD + ko);
    #pragma unroll
    for (int jc = 0; jc < 4; ++jc)
      bf[jc] = *reinterpret_cast<const bf16x8*>(Bm + (size_t)(j0 + jc * 16 + lr) * DHEAD + ko);
    #pragma unroll
    for (int ic = 0; ic < 4; ++ic)
      #pragma unroll
      for (int jc = 0; jc < 4; ++jc)
        acc[ic][jc] = __builtin_amdgcn_mfma_f32_16x16x32_bf16(af[ic], bf[jc], acc[ic][jc], 0, 0, 0);
  }

  // epilogue: D col = lane&15 -> j, row = (lane>>4)*4 + r -> i; pack 4 i's as 8B store
  const float NLOG2E = -1.44269504088896340736f;
  __half* Wp = W + (size_t)pb * (T1 * T1);
  int ib = kg << 2;
  #pragma unroll
  for (int ic = 0; ic < 4; ++ic) {
    int i = i0 + ic * 16 + ib;
    #pragma unroll
    for (int jc = 0; jc < 4; ++jc) {
      int j = j0 + jc * 16 + lr;
      union { __half h[4]; uint2 u; } pk;
      #pragma unroll
      for (int r = 0; r < 4; ++r) {
        float d = 1.0f - acc[ic][jc][r];
        pk.h[r] = __float2half(exp2f(NLOG2E * d));
      }
      *reinterpret_cast<uint2*>(Wp + (size_t)j * T1 + i) = pk.u;
    }
  }
}

// ---------------- kernel 3: soft-DTW, exp domain, skew-2, paired delayed shuffles ----------------
// Lane l owns DP rows 8l+1..8l+8, processes W col j = t - 2l at step t.
// Neighbor needs: up = neighbor bottom row at col j  = neighbor's V7d0 (1-delay capture),
//                 diag = same at col j-1              = neighbor's V7d1 (2-delay capture).
// Each delayed value is shuffled WITH the base captured at the same time; ldexp converts
// exactly into my base. Exponent clamp +-160 makes inf structurally impossible.
// Per-cell = 1 chained FMA; renorm by exact power-of-2 every 8 steps.
__global__ __launch_bounds__(64) void k_dtw(const __half* __restrict__ W,
                                            float* __restrict__ res) {
  int prob = blockIdx.x;
  const __half* Wp = W + (size_t)prob * (T1 * T1);
  int lane = threadIdx.x;
  const __half* lp = Wp + (lane << 3);

  float V[8];
  #pragma unroll
  for (int r = 0; r < 8; ++r) V[r] = 0.f;
  float B2 = 0.f;                          // base, log2 units (integer-valued, exact)
  float V7d0 = 0.f, V7d1 = 0.f;            // V[7] delay line (capture at step top)
  float B2d0 = 0.f, B2d1 = 0.f;            // matching bases

  auto loadW = [&](int t) -> uint4 {
    int j = t - 2 * lane;
    j = j < 0 ? 0 : (j > T1 - 1 ? T1 - 1 : j);
    return *reinterpret_cast<const uint4*>(lp + (size_t)j * T1);
  };

  auto step = [&](int t, uint4 raw, bool renorm) {
    // read neighbor delayed pairs (state as of end of step t-1), then shift my line
    float nbUp  = __shfl_up(V7d0, 1);   // neighbor col j   (up)
    float nbUpB = __shfl_up(B2d0, 1);
    float nbDg  = __shfl_up(V7d1, 1);   // neighbor col j-1 (diag)
    float nbDgB = __shfl_up(B2d1, 1);
    V7d1 = V7d0; V7d0 = V[7];
    B2d1 = B2d0; B2d0 = B2;
    if (lane == 0) {                    // DP row 0 boundary: E=0 except E[0][0]=1
      nbUp = 0.f; nbUpB = B2;
      nbDg = (t == 0) ? 1.f : 0.f; nbDgB = B2;
    }
    int du = (int)(B2 - nbUpB); du = du > 160 ? 160 : (du < -160 ? -160 : du);
    int dd = (int)(B2 - nbDgB); dd = dd > 160 ? 160 : (dd < -160 ? -160 : dd);
    float up = ldexpf(nbUp, du);        // exact base conversion (power of 2)
    float dg = ldexpf(nbDg, dd);

    union { uint4 u; __half h[8]; } cv; cv.u = raw;
    float wv[8];
    #pragma unroll
    for (int r = 0; r < 8; ++r) wv[r] = __half2float(cv.h[r]);

    int j = t - 2 * lane;
    bool active = ((unsigned)j < (unsigned)T1);
    if (active) {
      float c = fmaf(wv[0], up, wv[0] * (dg + V[0]));
      float Vn[8]; Vn[0] = c;
      #pragma unroll
      for (int r = 1; r < 8; ++r) {
        c = fmaf(wv[r], c, wv[r] * (V[r-1] + V[r]));
        Vn[r] = c;
      }
      if (renorm) {
        float m = fmaxf(fmaxf(fmaxf(Vn[0], Vn[1]), fmaxf(Vn[2], Vn[3])),
                        fmaxf(fmaxf(Vn[4], Vn[5]), fmaxf(Vn[6], Vn[7])));
        int e = (int)((__float_as_uint(m) >> 23) & 0xFF) - 127;
        e = e < -126 ? -126 : (e > 126 ? 126 : e);
        float sc = __uint_as_float((unsigned)(127 - e) << 23);  // 2^(-e), exact
        #pragma unroll
        for (int r = 0; r < 8; ++r) V[r] = Vn[r] * sc;
        B2 -= (float)e;
      } else {
        #pragma unroll
        for (int r = 0; r < 8; ++r) V[r] = Vn[r];
      }
    }
  };

  uint4 bA[8], bB[8];
  #pragma unroll
  for (int k = 0; k < 8; ++k) bA[k] = loadW(k);
  #pragma unroll
  for (int k = 0; k < 8; ++k) bB[k] = loadW(8 + k);

  for (int tb = 0; tb < 640; tb += 16) {    // lane63 last active col at t=637
    #pragma unroll
    for (int k = 0; k < 8; ++k) {
      step(tb + k, bA[k], k == 7);
      bA[k] = loadW(tb + 16 + k);
    }
    __builtin_amdgcn_sched_barrier(0);      // pin prefetch distance
    #pragma unroll
    for (int k = 0; k < 8; ++k) {
      step(tb + 8 + k, bB[k], k == 7);
      bB[k] = loadW(tb + 24 + k);
    }
    __builtin_amdgcn_sched_barrier(0);
  }

  if (lane == 63) {
    res[prob] = (B2 - log2f(V[7])) * 0.69314718055994530942f;
  }
}

// ---------------- kernel 4: combine ----------------
__global__ void k_combine(const float* __restrict__ res, float* __restrict__ out) {
  int b = threadIdx.x;
  if (b < NB) out[b] = res[b] - 0.5f * (res[NB + b] + res[2 * NB + b]);
}

extern "C" void kernel_launch(void* const* d_in, const int* in_sizes, int n_in,
                              void* d_out, int out_size, void* d_ws, size_t ws_size,
                              hipStream_t stream) {
  const float* x = (const float*)d_in[0];
  const float* y = (const float*)d_in[1];
  float* out = (float*)d_out;

  const size_t xb_off  = 0;
  const size_t yb_off  = (size_t)NB * T1 * DHEAD * sizeof(ushort);           // 2 MB
  const size_t W_off   = 2 * yb_off;                                          // 4 MB
  const size_t res_off = W_off + (size_t)3 * NB * T1 * T1 * sizeof(__half);   // +50.33 MB
  const size_t need    = res_off + NP * sizeof(float);

  if (ws_size < need) {
    hipMemsetAsync(d_out, 0xFF, (size_t)out_size * sizeof(float), stream);
    return;
  }

  ushort* xb  = (ushort*)((char*)d_ws + xb_off);
  ushort* yb  = (ushort*)((char*)d_ws + yb_off);
  __half* W   = (__half*)((char*)d_ws + W_off);
  float*  res = (float*)((char*)d_ws + res_off);

  hipLaunchKernelGGL(k_normalize, dim3(8192), dim3(256), 0, stream, x, y, xb, yb);
  hipLaunchKernelGGL(k_gemm_w, dim3(4, 4, 96), dim3(256), 0, stream, xb, yb, W);
  hipLaunchKernelGGL(k_dtw, dim3(NP), dim3(64), 0, stream, W, res);
  hipLaunchKernelGGL(k_combine, dim3(1), dim3(64), 0, stream, res, out);
}

// Round 5
// 127.935 us; speedup vs baseline: 1.5492x; 1.0005x over previous
//
#include <hip/hip_runtime.h>
#include <hip/hip_fp16.h>

#define T1 512
#define NB 32      // batches
#define NP 96      // 3 pairs * 32 batches
#define DHEAD 64

typedef __attribute__((ext_vector_type(8))) short bf16x8;
typedef __attribute__((ext_vector_type(4))) float f32x4;

// ---------------- kernel 1: row-normalize x,y -> bf16 ----------------
__global__ __launch_bounds__(256) void k_normalize(const float* __restrict__ x,
                                                   const float* __restrict__ y,
                                                   ushort* __restrict__ xb,
                                                   ushort* __restrict__ yb) {
  int wid  = threadIdx.x >> 6;
  int lane = threadIdx.x & 63;
  int row  = blockIdx.x * 4 + wid;          // 0 .. 32767
  const float* src; ushort* dst;
  if (row < NB * T1) { src = x + (size_t)row * DHEAD;            dst = xb + (size_t)row * DHEAD; }
  else { int r2 = row - NB * T1; src = y + (size_t)r2 * DHEAD;   dst = yb + (size_t)r2 * DHEAD; }
  float v = src[lane];
  float s = v * v;
  #pragma unroll
  for (int off = 32; off > 0; off >>= 1) s += __shfl_xor(s, off);
  float rn = 1.0f / fmaxf(sqrtf(s), 1e-12f);
  float o = v * rn;
  unsigned u = __float_as_uint(o);
  unsigned r = (u + 0x7fffu + ((u >> 16) & 1u)) >> 16;   // RNE to bf16
  dst[lane] = (ushort)r;
}

// ---------------- kernel 2: MFMA bf16 GEMM -> W[p][b][j][i] = exp(-(1-dot)) f16 ----------------
// 256 thr = 4 waves (2x2), tile 128x128, wave tile 64x64. K=64 = 2 mfma k-steps.
// Fragments loaded directly from global (xb/yb K-contiguous, L2-resident).
__global__ __launch_bounds__(256) void k_gemm_w(const ushort* __restrict__ xb,
                                                const ushort* __restrict__ yb,
                                                __half* __restrict__ W) {
  int pb = blockIdx.z;            // 0..95
  int p  = pb >> 5;               // 0:xy 1:xx 2:yy
  int b  = pb & 31;
  const ushort* A  = ((p == 2) ? yb : xb) + (size_t)b * T1 * DHEAD;  // i-side (M)
  const ushort* Bm = ((p == 1) ? xb : yb) + (size_t)b * T1 * DHEAD;  // j-side (N)

  int wid = threadIdx.x >> 6, lane = threadIdx.x & 63;
  int wm = wid >> 1, wn = wid & 1;
  int i0 = blockIdx.x * 128 + wm * 64;
  int j0 = blockIdx.y * 128 + wn * 64;
  int lr = lane & 15, kg = lane >> 4;

  f32x4 acc[4][4];
  #pragma unroll
  for (int ic = 0; ic < 4; ++ic)
    #pragma unroll
    for (int jc = 0; jc < 4; ++jc) acc[ic][jc] = (f32x4){0.f, 0.f, 0.f, 0.f};

  #pragma unroll
  for (int kk = 0; kk < 2; ++kk) {
    int ko = kk * 32 + kg * 8;
    bf16x8 af[4], bf[4];
    #pragma unroll
    for (int ic = 0; ic < 4; ++ic)
      af[ic] = *reinterpret_cast<const bf16x8*>(A + (size_t)(i0 + ic * 16 + lr) * DHEAD + ko);
    #pragma unroll
    for (int jc = 0; jc < 4; ++jc)
      bf[jc] = *reinterpret_cast<const bf16x8*>(Bm + (size_t)(j0 + jc * 16 + lr) * DHEAD + ko);
    #pragma unroll
    for (int ic = 0; ic < 4; ++ic)
      #pragma unroll
      for (int jc = 0; jc < 4; ++jc)
        acc[ic][jc] = __builtin_amdgcn_mfma_f32_16x16x32_bf16(af[ic], bf[jc], acc[ic][jc], 0, 0, 0);
  }

  // epilogue: D col = lane&15 -> j, row = (lane>>4)*4 + r -> i; pack 4 i's as 8B store
  const float NLOG2E = -1.44269504088896340736f;
  __half* Wp = W + (size_t)pb * (T1 * T1);
  int ib = kg << 2;
  #pragma unroll
  for (int ic = 0; ic < 4; ++ic) {
    int i = i0 + ic * 16 + ib;
    #pragma unroll
    for (int jc = 0; jc < 4; ++jc) {
      int j = j0 + jc * 16 + lr;
      union { __half h[4]; uint2 u; } pk;
      #pragma unroll
      for (int r = 0; r < 4; ++r) {
        float d = 1.0f - acc[ic][jc][r];
        pk.h[r] = __float2half(exp2f(NLOG2E * d));
      }
      *reinterpret_cast<uint2*>(Wp + (size_t)j * T1 + i) = pk.u;
    }
  }
}

// ---------------- kernel 3: soft-DTW, exp domain, skew-2, paired delayed shuffles ----------------
// Lane l owns DP rows 8l+1..8l+8, processes W col j = t - 2l at step t.
// Neighbor needs: up = neighbor bottom row at col j  = neighbor's V7d0 (1-delay capture),
//                 diag = same at col j-1              = neighbor's V7d1 (2-delay capture).
// Each delayed value is shuffled WITH the base captured at the same time; ldexp converts
// exactly into my base. Exponent clamp +-160 makes inf structurally impossible.
// Per-cell = 1 chained FMA; renorm by exact power-of-2 every 8 steps.
// __launch_bounds__(64, 1): occupancy is irrelevant (96 single-wave blocks on 256 CUs);
// lift the default 64-VGPR cap so the 16-deep prefetch (64 VGPRs of uint4) stays in
// registers. Round-4 counters (VGPR=52, 342 cyc/step) proved the cap killed the prefetch.
__global__ __launch_bounds__(64, 1) void k_dtw(const __half* __restrict__ W,
                                               float* __restrict__ res) {
  int prob = blockIdx.x;
  const __half* Wp = W + (size_t)prob * (T1 * T1);
  int lane = threadIdx.x;
  const __half* lp = Wp + (lane << 3);

  float V[8];
  #pragma unroll
  for (int r = 0; r < 8; ++r) V[r] = 0.f;
  float B2 = 0.f;                          // base, log2 units (integer-valued, exact)
  float V7d0 = 0.f, V7d1 = 0.f;            // V[7] delay line (capture at step top)
  float B2d0 = 0.f, B2d1 = 0.f;            // matching bases

  auto loadW = [&](int t) -> uint4 {
    int j = t - 2 * lane;
    j = j < 0 ? 0 : (j > T1 - 1 ? T1 - 1 : j);
    return *reinterpret_cast<const uint4*>(lp + (size_t)j * T1);
  };

  auto step = [&](int t, uint4 raw, bool renorm) {
    // read neighbor delayed pairs (state as of end of step t-1), then shift my line
    float nbUp  = __shfl_up(V7d0, 1);   // neighbor col j   (up)
    float nbUpB = __shfl_up(B2d0, 1);
    float nbDg  = __shfl_up(V7d1, 1);   // neighbor col j-1 (diag)
    float nbDgB = __shfl_up(B2d1, 1);
    V7d1 = V7d0; V7d0 = V[7];
    B2d1 = B2d0; B2d0 = B2;
    if (lane == 0) {                    // DP row 0 boundary: E=0 except E[0][0]=1
      nbUp = 0.f; nbUpB = B2;
      nbDg = (t == 0) ? 1.f : 0.f; nbDgB = B2;
    }
    int du = (int)(B2 - nbUpB); du = du > 160 ? 160 : (du < -160 ? -160 : du);
    int dd = (int)(B2 - nbDgB); dd = dd > 160 ? 160 : (dd < -160 ? -160 : dd);
    float up = ldexpf(nbUp, du);        // exact base conversion (power of 2)
    float dg = ldexpf(nbDg, dd);

    union { uint4 u; __half h[8]; } cv; cv.u = raw;
    float wv[8];
    #pragma unroll
    for (int r = 0; r < 8; ++r) wv[r] = __half2float(cv.h[r]);

    int j = t - 2 * lane;
    bool active = ((unsigned)j < (unsigned)T1);
    if (active) {
      float c = fmaf(wv[0], up, wv[0] * (dg + V[0]));
      float Vn[8]; Vn[0] = c;
      #pragma unroll
      for (int r = 1; r < 8; ++r) {
        c = fmaf(wv[r], c, wv[r] * (V[r-1] + V[r]));
        Vn[r] = c;
      }
      if (renorm) {
        float m = fmaxf(fmaxf(fmaxf(Vn[0], Vn[1]), fmaxf(Vn[2], Vn[3])),
                        fmaxf(fmaxf(Vn[4], Vn[5]), fmaxf(Vn[6], Vn[7])));
        int e = (int)((__float_as_uint(m) >> 23) & 0xFF) - 127;
        e = e < -126 ? -126 : (e > 126 ? 126 : e);
        float sc = __uint_as_float((unsigned)(127 - e) << 23);  // 2^(-e), exact
        #pragma unroll
        for (int r = 0; r < 8; ++r) V[r] = Vn[r] * sc;
        B2 -= (float)e;
      } else {
        #pragma unroll
        for (int r = 0; r < 8; ++r) V[r] = Vn[r];
      }
    }
  };

  uint4 bA[8], bB[8];
  #pragma unroll
  for (int k = 0; k < 8; ++k) bA[k] = loadW(k);
  #pragma unroll
  for (int k = 0; k < 8; ++k) bB[k] = loadW(8 + k);

  for (int tb = 0; tb < 640; tb += 16) {    // lane63 last active col at t=637
    #pragma unroll
    for (int k = 0; k < 8; ++k) {
      step(tb + k, bA[k], k == 7);
      bA[k] = loadW(tb + 16 + k);
    }
    __builtin_amdgcn_sched_barrier(0);      // pin prefetch distance
    #pragma unroll
    for (int k = 0; k < 8; ++k) {
      step(tb + 8 + k, bB[k], k == 7);
      bB[k] = loadW(tb + 24 + k);
    }
    __builtin_amdgcn_sched_barrier(0);
  }

  if (lane == 63) {
    res[prob] = (B2 - log2f(V[7])) * 0.69314718055994530942f;
  }
}

// ---------------- kernel 4: combine ----------------
__global__ void k_combine(const float* __restrict__ res, float* __restrict__ out) {
  int b = threadIdx.x;
  if (b < NB) out[b] = res[b] - 0.5f * (res[NB + b] + res[2 * NB + b]);
}

extern "C" void kernel_launch(void* const* d_in, const int* in_sizes, int n_in,
                              void* d_out, int out_size, void* d_ws, size_t ws_size,
                              hipStream_t stream) {
  const float* x = (const float*)d_in[0];
  const float* y = (const float*)d_in[1];
  float* out = (float*)d_out;

  const size_t xb_off  = 0;
  const size_t yb_off  = (size_t)NB * T1 * DHEAD * sizeof(ushort);           // 2 MB
  const size_t W_off   = 2 * yb_off;                                          // 4 MB
  const size_t res_off = W_off + (size_t)3 * NB * T1 * T1 * sizeof(__half);   // +50.33 MB
  const size_t need    = res_off + NP * sizeof(float);

  if (ws_size < need) {
    hipMemsetAsync(d_out, 0xFF, (size_t)out_size * sizeof(float), stream);
    return;
  }

  ushort* xb  = (ushort*)((char*)d_ws + xb_off);
  ushort* yb  = (ushort*)((char*)d_ws + yb_off);
  __half* W   = (__half*)((char*)d_ws + W_off);
  float*  res = (float*)((char*)d_ws + res_off);

  hipLaunchKernelGGL(k_normalize, dim3(8192), dim3(256), 0, stream, x, y, xb, yb);
  hipLaunchKernelGGL(k_gemm_w, dim3(4, 4, 96), dim3(256), 0, stream, xb, yb, W);
  hipLaunchKernelGGL(k_dtw, dim3(NP), dim3(64), 0, stream, W, res);
  hipLaunchKernelGGL(k_combine, dim3(1), dim3(64), 0, stream, res, out);
}

// Round 6
// 126.591 us; speedup vs baseline: 1.5656x; 1.0106x over previous
//
#include <hip/hip_runtime.h>
#include <hip/hip_fp16.h>

#define T1 512
#define NB 32      // batches
#define NP 96      // 3 pairs * 32 batches
#define DHEAD 64

typedef __attribute__((ext_vector_type(8))) short bf16x8;
typedef __attribute__((ext_vector_type(4))) float f32x4;
typedef __attribute__((ext_vector_type(4))) unsigned int u32x4;

// ---------------- kernel 1: row-normalize x,y -> bf16 ----------------
__global__ __launch_bounds__(256) void k_normalize(const float* __restrict__ x,
                                                   const float* __restrict__ y,
                                                   ushort* __restrict__ xb,
                                                   ushort* __restrict__ yb) {
  int wid  = threadIdx.x >> 6;
  int lane = threadIdx.x & 63;
  int row  = blockIdx.x * 4 + wid;          // 0 .. 32767
  const float* src; ushort* dst;
  if (row < NB * T1) { src = x + (size_t)row * DHEAD;            dst = xb + (size_t)row * DHEAD; }
  else { int r2 = row - NB * T1; src = y + (size_t)r2 * DHEAD;   dst = yb + (size_t)r2 * DHEAD; }
  float v = src[lane];
  float s = v * v;
  #pragma unroll
  for (int off = 32; off > 0; off >>= 1) s += __shfl_xor(s, off);
  float rn = 1.0f / fmaxf(sqrtf(s), 1e-12f);
  float o = v * rn;
  unsigned u = __float_as_uint(o);
  unsigned r = (u + 0x7fffu + ((u >> 16) & 1u)) >> 16;   // RNE to bf16
  dst[lane] = (ushort)r;
}

// ---------------- kernel 2: MFMA bf16 GEMM -> W[p][b][j][i] = exp(-(1-dot)) f16 ----------------
// 256 thr = 4 waves (2x2), tile 128x128, wave tile 64x64. K=64 = 2 mfma k-steps.
// Fragments loaded directly from global (xb/yb K-contiguous, L2-resident).
__global__ __launch_bounds__(256) void k_gemm_w(const ushort* __restrict__ xb,
                                                const ushort* __restrict__ yb,
                                                __half* __restrict__ W) {
  int pb = blockIdx.z;            // 0..95
  int p  = pb >> 5;               // 0:xy 1:xx 2:yy
  int b  = pb & 31;
  const ushort* A  = ((p == 2) ? yb : xb) + (size_t)b * T1 * DHEAD;  // i-side (M)
  const ushort* Bm = ((p == 1) ? xb : yb) + (size_t)b * T1 * DHEAD;  // j-side (N)

  int wid = threadIdx.x >> 6, lane = threadIdx.x & 63;
  int wm = wid >> 1, wn = wid & 1;
  int i0 = blockIdx.x * 128 + wm * 64;
  int j0 = blockIdx.y * 128 + wn * 64;
  int lr = lane & 15, kg = lane >> 4;

  f32x4 acc[4][4];
  #pragma unroll
  for (int ic = 0; ic < 4; ++ic)
    #pragma unroll
    for (int jc = 0; jc < 4; ++jc) acc[ic][jc] = (f32x4){0.f, 0.f, 0.f, 0.f};

  #pragma unroll
  for (int kk = 0; kk < 2; ++kk) {
    int ko = kk * 32 + kg * 8;
    bf16x8 af[4], bf[4];
    #pragma unroll
    for (int ic = 0; ic < 4; ++ic)
      af[ic] = *reinterpret_cast<const bf16x8*>(A + (size_t)(i0 + ic * 16 + lr) * DHEAD + ko);
    #pragma unroll
    for (int jc = 0; jc < 4; ++jc)
      bf[jc] = *reinterpret_cast<const bf16x8*>(Bm + (size_t)(j0 + jc * 16 + lr) * DHEAD + ko);
    #pragma unroll
    for (int ic = 0; ic < 4; ++ic)
      #pragma unroll
      for (int jc = 0; jc < 4; ++jc)
        acc[ic][jc] = __builtin_amdgcn_mfma_f32_16x16x32_bf16(af[ic], bf[jc], acc[ic][jc], 0, 0, 0);
  }

  // epilogue: D col = lane&15 -> j, row = (lane>>4)*4 + r -> i; pack 4 i's as 8B store
  const float NLOG2E = -1.44269504088896340736f;
  __half* Wp = W + (size_t)pb * (T1 * T1);
  int ib = kg << 2;
  #pragma unroll
  for (int ic = 0; ic < 4; ++ic) {
    int i = i0 + ic * 16 + ib;
    #pragma unroll
    for (int jc = 0; jc < 4; ++jc) {
      int j = j0 + jc * 16 + lr;
      union { __half h[4]; uint2 u; } pk;
      #pragma unroll
      for (int r = 0; r < 4; ++r) {
        float d = 1.0f - acc[ic][jc][r];
        pk.h[r] = __float2half(exp2f(NLOG2E * d));
      }
      *reinterpret_cast<uint2*>(Wp + (size_t)j * T1 + i) = pk.u;
    }
  }
}

// ---------------- kernel 3: soft-DTW, exp domain, skew-2, asm-forced 32-deep pipeline -------
// DP math identical to the absmax-0.0 round-4 version. The prefetch is now un-deletable:
//  - loads are `asm volatile global_load_dwordx4` into a 32-slot register window (asm
//    outputs must live in registers; volatile order = issue order, so vmcnt counts exactly);
//  - before consuming slot k: `s_waitcnt vmcnt(31)` as asm with "+v"(slot) — the register
//    dependency orders load -> wait -> consume without fencing unrelated work (rule #18).
// Steady state: 32 loads in flight; each has 32 steps (~2000 cyc) to cover ~900cyc HBM.
__global__ __launch_bounds__(64, 1) void k_dtw(const __half* __restrict__ W,
                                               float* __restrict__ res) {
  int prob = blockIdx.x;
  const __half* Wp = W + (size_t)prob * (T1 * T1);
  int lane = threadIdx.x;
  const __half* lp = Wp + (lane << 3);     // lane's 16B slice of each 1KB column

  float V[8];
  #pragma unroll
  for (int r = 0; r < 8; ++r) V[r] = 0.f;
  float B2 = 0.f;                          // base, log2 units (integer-valued, exact)
  float V7d0 = 0.f, V7d1 = 0.f;            // V[7] delay line (capture at step top)
  float B2d0 = 0.f, B2d1 = 0.f;            // matching bases

#define LOADW(dst, t) do {                                               \
    int j_ = (t) - 2 * lane;                                             \
    j_ = j_ < 0 ? 0 : (j_ > T1 - 1 ? T1 - 1 : j_);                       \
    const __half* a_ = lp + ((size_t)j_ << 9);                           \
    asm volatile("global_load_dwordx4 %0, %1, off"                       \
                 : "=v"(dst) : "v"(a_));                                 \
  } while (0)

#define WAITW(v4) asm volatile("s_waitcnt vmcnt(31)" : "+v"(v4))

  auto step = [&](int t, u32x4 raw, bool renorm) {
    // read neighbor delayed pairs (state as of end of step t-1), then shift my line
    float nbUp  = __shfl_up(V7d0, 1);   // neighbor col j   (up)
    float nbUpB = __shfl_up(B2d0, 1);
    float nbDg  = __shfl_up(V7d1, 1);   // neighbor col j-1 (diag)
    float nbDgB = __shfl_up(B2d1, 1);
    V7d1 = V7d0; V7d0 = V[7];
    B2d1 = B2d0; B2d0 = B2;
    if (lane == 0) {                    // DP row 0 boundary: E=0 except E[0][0]=1
      nbUp = 0.f; nbUpB = B2;
      nbDg = (t == 0) ? 1.f : 0.f; nbDgB = B2;
    }
    int du = (int)(B2 - nbUpB); du = du > 160 ? 160 : (du < -160 ? -160 : du);
    int dd = (int)(B2 - nbDgB); dd = dd > 160 ? 160 : (dd < -160 ? -160 : dd);
    float up = ldexpf(nbUp, du);        // exact base conversion (power of 2)
    float dg = ldexpf(nbDg, dd);

    union { u32x4 u; __half h[8]; } cv; cv.u = raw;
    float wv[8];
    #pragma unroll
    for (int r = 0; r < 8; ++r) wv[r] = __half2float(cv.h[r]);

    int j = t - 2 * lane;
    bool active = ((unsigned)j < (unsigned)T1);
    if (active) {
      float c = fmaf(wv[0], up, wv[0] * (dg + V[0]));
      float Vn[8]; Vn[0] = c;
      #pragma unroll
      for (int r = 1; r < 8; ++r) {
        c = fmaf(wv[r], c, wv[r] * (V[r-1] + V[r]));
        Vn[r] = c;
      }
      if (renorm) {
        float m = fmaxf(fmaxf(fmaxf(Vn[0], Vn[1]), fmaxf(Vn[2], Vn[3])),
                        fmaxf(fmaxf(Vn[4], Vn[5]), fmaxf(Vn[6], Vn[7])));
        int e = (int)((__float_as_uint(m) >> 23) & 0xFF) - 127;
        e = e < -126 ? -126 : (e > 126 ? 126 : e);
        float sc = __uint_as_float((unsigned)(127 - e) << 23);  // 2^(-e), exact
        #pragma unroll
        for (int r = 0; r < 8; ++r) V[r] = Vn[r] * sc;
        B2 -= (float)e;
      } else {
        #pragma unroll
        for (int r = 0; r < 8; ++r) V[r] = Vn[r];
      }
    }
  };

  u32x4 buf[32];                       // only constant-indexed (fully unrolled) accesses
  #pragma unroll
  for (int k = 0; k < 32; ++k) LOADW(buf[k], k);

  for (int tb = 0; tb < 640; tb += 32) {   // lane63 last active col at t=637
    #pragma unroll
    for (int k = 0; k < 32; ++k) {
      WAITW(buf[k]);                       // oldest of 32 in flight is complete
      step(tb + k, buf[k], ((k & 7) == 7));
      LOADW(buf[k], tb + 32 + k);          // refill window, 32 steps ahead
    }
  }

  if (lane == 63) {
    res[prob] = (B2 - log2f(V[7])) * 0.69314718055994530942f;
  }
#undef LOADW
#undef WAITW
}

// ---------------- kernel 4: combine ----------------
__global__ void k_combine(const float* __restrict__ res, float* __restrict__ out) {
  int b = threadIdx.x;
  if (b < NB) out[b] = res[b] - 0.5f * (res[NB + b] + res[2 * NB + b]);
}

extern "C" void kernel_launch(void* const* d_in, const int* in_sizes, int n_in,
                              void* d_out, int out_size, void* d_ws, size_t ws_size,
                              hipStream_t stream) {
  const float* x = (const float*)d_in[0];
  const float* y = (const float*)d_in[1];
  float* out = (float*)d_out;

  const size_t xb_off  = 0;
  const size_t yb_off  = (size_t)NB * T1 * DHEAD * sizeof(ushort);           // 2 MB
  const size_t W_off   = 2 * yb_off;                                          // 4 MB
  const size_t res_off = W_off + (size_t)3 * NB * T1 * T1 * sizeof(__half);   // +50.33 MB
  const size_t need    = res_off + NP * sizeof(float);

  if (ws_size < need) {
    hipMemsetAsync(d_out, 0xFF, (size_t)out_size * sizeof(float), stream);
    return;
  }

  ushort* xb  = (ushort*)((char*)d_ws + xb_off);
  ushort* yb  = (ushort*)((char*)d_ws + yb_off);
  __half* W   = (__half*)((char*)d_ws + W_off);
  float*  res = (float*)((char*)d_ws + res_off);

  hipLaunchKernelGGL(k_normalize, dim3(8192), dim3(256), 0, stream, x, y, xb, yb);
  hipLaunchKernelGGL(k_gemm_w, dim3(4, 4, 96), dim3(256), 0, stream, xb, yb, W);
  hipLaunchKernelGGL(k_dtw, dim3(NP), dim3(64), 0, stream, W, res);
  hipLaunchKernelGGL(k_combine, dim3(1), dim3(64), 0, stream, res, out);
}